// Round 8
// baseline (486.656 us; speedup 1.0000x reference)
//
#include <hip/hip_runtime.h>

typedef __bf16 bf16_t;
typedef __bf16 bf16x8 __attribute__((ext_vector_type(8)));
typedef float floatx4 __attribute__((ext_vector_type(4)));

constexpr int N = 100000;   // nodes
constexpr int E = 1600000;  // edges
constexpr int H = 128;      // feature dim
constexpr int G = 64;       // graphs
constexpr int C = 10;       // classes
constexpr int NBLK = (N + 255) / 256;  // 391

// bucket/fill: 8 dst partitions, then 125 sub-buckets of 100 nodes each.
constexpr int FPART = 8;
constexpr int FPART_SZ = (N + FPART - 1) / FPART;  // 12500
constexpr int BCHUNK = 2048;                       // edges/block (8/thread)
constexpr int BBLK = (E + BCHUNK - 1) / BCHUNK;    // 782
constexpr int BCAP = 204800;  // per-part bucket cap (E/8 + 11sigma)

constexpr int SUBP = 125;         // sub-buckets per partition
constexpr int SUBSZ = 100;        // nodes per sub-bucket (8*125*100 == N)
constexpr int SB = FPART * SUBP;  // 1000
constexpr int SCAP = 2048;        // sub-bucket cap (mean 1600 + 11sigma)
constexpr int SCHUNK = 8192;      // entries per subbucket block-iteration

__device__ inline float bflo(unsigned u) {
  return __builtin_bit_cast(float, u << 16);
}
__device__ inline float bfhi(unsigned u) {
  return __builtin_bit_cast(float, u & 0xffff0000u);
}
__device__ inline unsigned short f2b(float f) {
  return __builtin_bit_cast(unsigned short, (bf16_t)f);
}
__device__ inline unsigned pack2(float a, float b) {
  return (unsigned)f2b(a) | ((unsigned)f2b(b) << 16);
}

// ---------------------------------------------------------------------------
// fp32 -> bf16 convert (x once per call).
// ---------------------------------------------------------------------------
__global__ __launch_bounds__(256) void tobf_kernel(const float* __restrict__ x,
                                                   uint4* __restrict__ xb) {
  const int g = blockIdx.x * 256 + threadIdx.x;
  const float4 a = *(const float4*)(x + (size_t)g * 8);
  const float4 b = *(const float4*)(x + (size_t)g * 8 + 4);
  uint4 o;
  o.x = pack2(a.x, a.y);
  o.y = pack2(a.z, a.w);
  o.z = pack2(b.x, b.y);
  o.w = pack2(b.z, b.w);
  xb[g] = o;
}

// ---------------------------------------------------------------------------
// Bucket pass v4: single edge-list read, ballot-rank slot assignment, LDS
// staging, coalesced partition-segment flush. No deg atomics.
// ---------------------------------------------------------------------------
__global__ __launch_bounds__(256) void bucket_kernel(
    const int* __restrict__ src, const int* __restrict__ dst,
    unsigned* __restrict__ buckets, int* __restrict__ bcnt) {
  __shared__ int offS[4][FPART];      // per-wave running counts
  __shared__ int waveExcl[4][FPART];  // per-wave exclusive base per part
  __shared__ int cntA[FPART];         // block totals per part
  __shared__ int blockExcl[FPART];    // in-block exclusive base per part
  __shared__ int baseS[FPART];        // global base per part
  __shared__ unsigned stage[BCHUNK];  // partition-ordered staging (8KB)
  const int tid = threadIdx.x;
  const int wave = tid >> 6;
  const int lane = tid & 63;
  if (tid < 32) ((int*)offS)[tid] = 0;
  __syncthreads();

  const int e0 = blockIdx.x * BCHUNK + tid * 8;
  int d[8], s[8];
  int nv = 0;
  if (e0 + 8 <= E) {
    const int4 da = *(const int4*)(dst + e0);
    const int4 db = *(const int4*)(dst + e0 + 4);
    const int4 sa = *(const int4*)(src + e0);
    const int4 sb = *(const int4*)(src + e0 + 4);
    d[0] = da.x; d[1] = da.y; d[2] = da.z; d[3] = da.w;
    d[4] = db.x; d[5] = db.y; d[6] = db.z; d[7] = db.w;
    s[0] = sa.x; s[1] = sa.y; s[2] = sa.z; s[3] = sa.w;
    s[4] = sb.x; s[5] = sb.y; s[6] = sb.z; s[7] = sb.w;
    nv = 8;
  } else {
    nv = (e0 < E) ? (E - e0) : 0;
    if (nv > 8) nv = 8;
    for (int j = 0; j < nv; ++j) {
      d[j] = dst[e0 + j];
      s[j] = src[e0 + j];
    }
    for (int j = nv; j < 8; ++j) { d[j] = 0; s[j] = 0; }
  }

  const unsigned long long below = (1ull << lane) - 1ull;

  int pj[8];     // partition of edge j
  int slotW[8];  // within-wave slot (base + rank)

#pragma unroll
  for (int j = 0; j < 8; ++j) {
    const bool valid = (j < nv);
    const int p = d[j] / FPART_SZ;
    pj[j] = p;
    unsigned long long mown = 0;
#pragma unroll
    for (int q = 0; q < FPART; ++q) {
      const unsigned long long mq = __ballot(valid && (p == q));
      if (p == q) mown = mq;
    }
    const int cnt = (int)__popcll(mown);
    const int rank = (int)__popcll(mown & below);
    const int base = offS[wave][p];
    if (valid && rank == 0) offS[wave][p] = base + cnt;
    slotW[j] = base + rank;
  }
  __syncthreads();

  // cross-wave scan + global reservation
  if (tid < FPART) {
    int running = 0;
#pragma unroll
    for (int w = 0; w < 4; ++w) {
      waveExcl[w][tid] = running;
      running += offS[w][tid];
    }
    cntA[tid] = running;
    baseS[tid] = atomicAdd(&bcnt[tid], running);
  }
  __syncthreads();
  if (tid < FPART) {
    int ex = 0;
    for (int q = 0; q < tid; ++q) ex += cntA[q];
    blockExcl[tid] = ex;
  }
  __syncthreads();

  // stage: partition-contiguous order within the block
#pragma unroll
  for (int j = 0; j < 8; ++j) {
    if (j < nv) {
      const int p = pj[j];
      stage[blockExcl[p] + waveExcl[wave][p] + slotW[j]] =
          ((unsigned)s[j] << 14) | (unsigned)(d[j] - p * FPART_SZ);
    }
  }
  __syncthreads();

  // flush: coalesced contiguous stores per partition segment
#pragma unroll
  for (int p = 0; p < FPART; ++p) {
    const int c = cntA[p];
    const int gb = p * BCAP + baseS[p];
    const int lb = blockExcl[p];
    for (int i = tid; i < c; i += 256) buckets[gb + i] = stage[lb + i];
  }
}

// ---------------------------------------------------------------------------
// Sub-bucket pass: partition buckets -> 1000 sub-buckets of exactly 100
// nodes. LDS count, LDS scan, staged coalesced segmented flush.
// ---------------------------------------------------------------------------
__global__ __launch_bounds__(256) void subbucket_kernel(
    const unsigned* __restrict__ buckets, const int* __restrict__ bcnt,
    unsigned* __restrict__ subbuck, int* __restrict__ sbcnt) {
  __shared__ unsigned stage[SCHUNK];  // 32 KB
  __shared__ int cntA[SUBP];
  __shared__ int cntB[SUBP];
  __shared__ int exclS[SUBP];
  __shared__ int gbase[SUBP];
  __shared__ int scanbuf[128];
  const int part = blockIdx.x & (FPART - 1);
  const int blk = blockIdx.x >> 3;
  const int nblk = gridDim.x >> 3;
  const int tid = threadIdx.x;
  const int cnt = bcnt[part];
  const unsigned* b = buckets + part * BCAP;

  for (int c0 = blk * SCHUNK; c0 < cnt; c0 += nblk * SCHUNK) {
    const int m = min(SCHUNK, cnt - c0);
    if (tid < SUBP) {
      cntA[tid] = 0;
      cntB[tid] = 0;
    }
    __syncthreads();
    // pass A: count per sub-bucket
    for (int i = tid; i < m; i += 256) {
      const unsigned ent = b[c0 + i];
      atomicAdd(&cntA[(int)(ent & 0x3FFFu) / SUBSZ], 1);
    }
    __syncthreads();
    // scan over 125 (Hillis-Steele on 128)
    if (tid < 128) scanbuf[tid] = (tid < SUBP) ? cntA[tid] : 0;
    __syncthreads();
    for (int off = 1; off < 128; off <<= 1) {
      int v = 0;
      if (tid < 128 && tid >= off) v = scanbuf[tid - off];
      __syncthreads();
      if (tid < 128) scanbuf[tid] += v;
      __syncthreads();
    }
    if (tid < SUBP) {
      exclS[tid] = scanbuf[tid] - cntA[tid];
      gbase[tid] = atomicAdd(&sbcnt[part * SUBP + tid], cntA[tid]);
    }
    __syncthreads();
    // pass B: place into LDS stage, sub-bucket-ordered (re-read is L2-hot)
    for (int i = tid; i < m; i += 256) {
      const unsigned ent = b[c0 + i];
      const int s = (int)(ent & 0x3FFFu) / SUBSZ;
      const int r = atomicAdd(&cntB[s], 1);
      stage[exclS[s] + r] = ent;
    }
    __syncthreads();
    // flush: coalesced within each sub-bucket segment
    for (int i = tid; i < m; i += 256) {
      const unsigned ent = stage[i];
      const int s = (int)(ent & 0x3FFFu) / SUBSZ;
      subbuck[(size_t)(part * SUBP + s) * SCAP + gbase[s] + (i - exclS[s])] =
          ent;
    }
    __syncthreads();
  }
}

// ---------------------------------------------------------------------------
// Scan of the 1000 sub-bucket counts -> exclusive bases (coarse rowptr).
// ---------------------------------------------------------------------------
__global__ __launch_bounds__(1024) void sbscan_kernel(
    const int* __restrict__ sbcnt, int* __restrict__ sbbase) {
  __shared__ int p[1024];
  const int t = threadIdx.x;
  p[t] = (t < SB) ? sbcnt[t] : 0;
  __syncthreads();
  for (int off = 1; off < 1024; off <<= 1) {
    int v = 0;
    if (t >= off) v = p[t - off];
    __syncthreads();
    p[t] += v;
    __syncthreads();
  }
  if (t < SB) sbbase[t] = p[t] - sbcnt[t];
}

// ---------------------------------------------------------------------------
// Fill v4: one block per sub-bucket. LDS counting sort over 100 nodes;
// local histogram scan yields rowptr for free; contiguous coalesced store.
// ---------------------------------------------------------------------------
__global__ __launch_bounds__(256) void fill3_kernel(
    const unsigned* __restrict__ subbuck, const int* __restrict__ sbcnt,
    const int* __restrict__ sbbase, int* __restrict__ rowptr,
    int* __restrict__ csr_src) {
  __shared__ unsigned ld[SCAP];  // 8 KB
  __shared__ int stageS[SCAP];   // 8 KB
  __shared__ int hist[SUBSZ];
  __shared__ int cntB[SUBSZ];
  __shared__ int exclS[SUBSZ];
  __shared__ int scanbuf[128];
  const int sb = blockIdx.x;
  const int part = sb / SUBP;
  const int subl = sb % SUBP;
  const int n0 = part * FPART_SZ + subl * SUBSZ;
  const int tid = threadIdx.x;
  const int cnt = sbcnt[sb];
  const int base = sbbase[sb];
  const unsigned* b = subbuck + (size_t)sb * SCAP;
  if (tid < SUBSZ) {
    hist[tid] = 0;
    cntB[tid] = 0;
  }
  __syncthreads();
  for (int i = tid; i < cnt; i += 256) {
    const unsigned ent = b[i];
    ld[i] = ent;
    atomicAdd(&hist[(int)(ent & 0x3FFFu) - subl * SUBSZ], 1);
  }
  __syncthreads();
  if (tid < 128) scanbuf[tid] = (tid < SUBSZ) ? hist[tid] : 0;
  __syncthreads();
  for (int off = 1; off < 128; off <<= 1) {
    int v = 0;
    if (tid < 128 && tid >= off) v = scanbuf[tid - off];
    __syncthreads();
    if (tid < 128) scanbuf[tid] += v;
    __syncthreads();
  }
  if (tid < SUBSZ) {
    const int ex = scanbuf[tid] - hist[tid];
    exclS[tid] = ex;
    rowptr[n0 + tid] = base + ex;  // per-node rowptr, derived locally
  }
  if (sb == SB - 1 && tid == 0) rowptr[N] = base + cnt;
  __syncthreads();
  for (int i = tid; i < cnt; i += 256) {
    const unsigned ent = ld[i];
    const int j = (int)(ent & 0x3FFFu) - subl * SUBSZ;
    const int r = atomicAdd(&cntB[j], 1);
    stageS[exclS[j] + r] = (int)(ent >> 14);
  }
  __syncthreads();
  for (int i = tid; i < cnt; i += 256) csr_src[base + i] = stageS[i];
}

// ---------------------------------------------------------------------------
// Gather aggregation (bf16), software-pipelined: per 4-edge group, next
// group's INDICES are loaded and ROW loads issued before accumulating the
// current group's rows (which were issued a full iteration earlier and have
// absorbed their miss latency). Breaks the idx->row->acc serial chain that
// capped the naive loop at ~3.6 TB/s. 16 lanes/node, uint4/lane.
// ---------------------------------------------------------------------------
__global__ __launch_bounds__(256) void gather_kernel(
    const uint4* __restrict__ h, const int* __restrict__ rowptr,
    const int* __restrict__ csr_src, uint4* __restrict__ pre) {
  const int node = blockIdx.x * 16 + (threadIdx.x >> 4);
  const int l = threadIdx.x & 15;
  const uint4 v = h[(size_t)node * 16 + l];
  const int r0 = rowptr[node];
  const int r1 = rowptr[node + 1];
  float a0 = bflo(v.x), a1 = bfhi(v.x), a2 = bflo(v.y), a3 = bfhi(v.y);
  float a4 = bflo(v.z), a5 = bfhi(v.z), a6 = bflo(v.w), a7 = bfhi(v.w);

  const int ng = (r1 - r0) >> 2;  // full 4-groups
  int s = r0;
  if (ng > 0) {
    // prologue: group 0 indices + rows in flight
    int i0 = csr_src[s], i1 = csr_src[s + 1];
    int i2 = csr_src[s + 2], i3 = csr_src[s + 3];
    uint4 c0 = h[(size_t)i0 * 16 + l];
    uint4 c1 = h[(size_t)i1 * 16 + l];
    uint4 c2 = h[(size_t)i2 * 16 + l];
    uint4 c3 = h[(size_t)i3 * 16 + l];
    for (int g = 0; g < ng; ++g) {
      const bool more = (g + 1 < ng);
      const int sn = s + 4;
      int j0 = 0, j1 = 0, j2 = 0, j3 = 0;
      uint4 n0, n1, n2, n3;
      if (more) {
        // issue next group's idx + rows BEFORE accumulating current rows
        j0 = csr_src[sn]; j1 = csr_src[sn + 1];
        j2 = csr_src[sn + 2]; j3 = csr_src[sn + 3];
        n0 = h[(size_t)j0 * 16 + l];
        n1 = h[(size_t)j1 * 16 + l];
        n2 = h[(size_t)j2 * 16 + l];
        n3 = h[(size_t)j3 * 16 + l];
      }
      // accumulate current rows (issued last iteration -> latency absorbed)
      a0 += bflo(c0.x); a1 += bfhi(c0.x); a2 += bflo(c0.y); a3 += bfhi(c0.y);
      a4 += bflo(c0.z); a5 += bfhi(c0.z); a6 += bflo(c0.w); a7 += bfhi(c0.w);
      a0 += bflo(c1.x); a1 += bfhi(c1.x); a2 += bflo(c1.y); a3 += bfhi(c1.y);
      a4 += bflo(c1.z); a5 += bfhi(c1.z); a6 += bflo(c1.w); a7 += bfhi(c1.w);
      a0 += bflo(c2.x); a1 += bfhi(c2.x); a2 += bflo(c2.y); a3 += bfhi(c2.y);
      a4 += bflo(c2.z); a5 += bfhi(c2.z); a6 += bflo(c2.w); a7 += bfhi(c2.w);
      a0 += bflo(c3.x); a1 += bfhi(c3.x); a2 += bflo(c3.y); a3 += bfhi(c3.y);
      a4 += bflo(c3.z); a5 += bfhi(c3.z); a6 += bflo(c3.w); a7 += bfhi(c3.w);
      if (more) {
        c0 = n0; c1 = n1; c2 = n2; c3 = n3;
      }
      s = sn;
    }
  }
  for (; s < r1; ++s) {
    const uint4 u = h[(size_t)csr_src[s] * 16 + l];
    a0 += bflo(u.x); a1 += bfhi(u.x); a2 += bflo(u.y); a3 += bfhi(u.y);
    a4 += bflo(u.z); a5 += bfhi(u.z); a6 += bflo(u.w); a7 += bfhi(u.w);
  }
  uint4 o;
  o.x = pack2(a0, a1);
  o.y = pack2(a2, a3);
  o.z = pack2(a4, a5);
  o.w = pack2(a6, a7);
  pre[(size_t)node * 16 + l] = o;
}

// ---------------------------------------------------------------------------
// MFMA bf16 GIN MLP (separate from gather: fusion costs gather occupancy,
// measured R6). Launched with N/32 blocks: exactly 1 tile/block (no tail
// imbalance). preS + hidS bf16 136-padded + LN stats = 17.7 KB.
// MODE 0: h_out = bf16(LN(relu(o))); MODE 1: emb = o, h_out = relu(o).
// ---------------------------------------------------------------------------
template <int MODE>
__global__ __launch_bounds__(256) void mlp_kernel(
    const unsigned short* __restrict__ pre_g,  // bf16 N x 128
    const float* __restrict__ w1, const float* __restrict__ b1,
    const float* __restrict__ w2, const float* __restrict__ b2,
    const float* __restrict__ lng, const float* __restrict__ lnb,
    unsigned short* __restrict__ h_out,        // bf16 N x 128
    float* __restrict__ emb) {
  __shared__ unsigned short preS[32 * 136];
  __shared__ unsigned short hidS[32 * 136];
  __shared__ float muS[32];
  __shared__ float rsS[32];

  const int tid = threadIdx.x;
  const int wave = tid >> 6;
  const int lane = tid & 63;
  const int quad = lane >> 4;
  const int l16 = lane & 15;

  union F8 { bf16x8 v; bf16_t e[8]; };

  bf16x8 w1f[4][2], w2f[4][2];
#pragma unroll
  for (int nn = 0; nn < 2; ++nn) {
    const int col = wave * 32 + nn * 16 + l16;
#pragma unroll
    for (int kt = 0; kt < 4; ++kt) {
      F8 t1, t2;
#pragma unroll
      for (int j = 0; j < 8; ++j) {
        const int k = kt * 32 + quad * 8 + j;
        t1.e[j] = (bf16_t)w1[k * H + col];
        t2.e[j] = (bf16_t)w2[k * H + col];
      }
      w1f[kt][nn] = t1.v;
      w2f[kt][nn] = t2.v;
    }
  }
  const float b1v[2] = {b1[wave * 32 + l16], b1[wave * 32 + 16 + l16]};
  const float b2v[2] = {b2[wave * 32 + l16], b2[wave * 32 + 16 + l16]};
  float lng0 = 0.f, lng1 = 0.f, lnb0 = 0.f, lnb1 = 0.f;
  const int c2 = (tid * 2) & 127;
  if (MODE == 0) {
    lng0 = lng[c2]; lng1 = lng[c2 + 1];
    lnb0 = lnb[c2]; lnb1 = lnb[c2 + 1];
  }

  for (int tile = blockIdx.x; tile < N / 32; tile += gridDim.x) {
    const size_t base = (size_t)tile * 32 * H;
    {
      const uint4* srcp = (const uint4*)(pre_g + base);
#pragma unroll
      for (int it = 0; it < 2; ++it) {
        const int chunk = it * 256 + tid;
        const int row = chunk >> 4;
        const int colc = (chunk & 15) * 8;
        *(uint4*)&preS[row * 136 + colc] = srcp[chunk];
      }
    }
    __syncthreads();

    // GEMM1: hid = relu(pre @ W1 + b1)
    {
      floatx4 acc[2][2];
#pragma unroll
      for (int i = 0; i < 2; ++i)
#pragma unroll
        for (int j = 0; j < 2; ++j) acc[i][j] = {0.f, 0.f, 0.f, 0.f};
#pragma unroll
      for (int kt = 0; kt < 4; ++kt) {
        const int kc = kt * 32 + quad * 8;
        const bf16x8 a0 =
            __builtin_bit_cast(bf16x8, *(const uint4*)&preS[l16 * 136 + kc]);
        const bf16x8 a1 = __builtin_bit_cast(
            bf16x8, *(const uint4*)&preS[(16 + l16) * 136 + kc]);
        acc[0][0] = __builtin_amdgcn_mfma_f32_16x16x32_bf16(a0, w1f[kt][0],
                                                            acc[0][0], 0, 0, 0);
        acc[0][1] = __builtin_amdgcn_mfma_f32_16x16x32_bf16(a0, w1f[kt][1],
                                                            acc[0][1], 0, 0, 0);
        acc[1][0] = __builtin_amdgcn_mfma_f32_16x16x32_bf16(a1, w1f[kt][0],
                                                            acc[1][0], 0, 0, 0);
        acc[1][1] = __builtin_amdgcn_mfma_f32_16x16x32_bf16(a1, w1f[kt][1],
                                                            acc[1][1], 0, 0, 0);
      }
#pragma unroll
      for (int mt = 0; mt < 2; ++mt)
#pragma unroll
        for (int nn = 0; nn < 2; ++nn) {
          const int col = wave * 32 + nn * 16 + l16;
#pragma unroll
          for (int r = 0; r < 4; ++r) {
            const int row = mt * 16 + quad * 4 + r;
            const float v = fmaxf(acc[mt][nn][r] + b1v[nn], 0.f);
            hidS[row * 136 + col] = f2b(v);
          }
        }
    }
    __syncthreads();  // hidS ready; also: all preS reads (GEMM1) done

    // GEMM2: o = hid @ W2 + b2 ; write o (bf16) back into preS
    {
      floatx4 acc[2][2];
#pragma unroll
      for (int i = 0; i < 2; ++i)
#pragma unroll
        for (int j = 0; j < 2; ++j) acc[i][j] = {0.f, 0.f, 0.f, 0.f};
#pragma unroll
      for (int kt = 0; kt < 4; ++kt) {
        const int kc = kt * 32 + quad * 8;
        const bf16x8 a0 =
            __builtin_bit_cast(bf16x8, *(const uint4*)&hidS[l16 * 136 + kc]);
        const bf16x8 a1 = __builtin_bit_cast(
            bf16x8, *(const uint4*)&hidS[(16 + l16) * 136 + kc]);
        acc[0][0] = __builtin_amdgcn_mfma_f32_16x16x32_bf16(a0, w2f[kt][0],
                                                            acc[0][0], 0, 0, 0);
        acc[0][1] = __builtin_amdgcn_mfma_f32_16x16x32_bf16(a0, w2f[kt][1],
                                                            acc[0][1], 0, 0, 0);
        acc[1][0] = __builtin_amdgcn_mfma_f32_16x16x32_bf16(a1, w2f[kt][0],
                                                            acc[1][0], 0, 0, 0);
        acc[1][1] = __builtin_amdgcn_mfma_f32_16x16x32_bf16(a1, w2f[kt][1],
                                                            acc[1][1], 0, 0, 0);
      }
#pragma unroll
      for (int mt = 0; mt < 2; ++mt)
#pragma unroll
        for (int nn = 0; nn < 2; ++nn) {
          const int col = wave * 32 + nn * 16 + l16;
#pragma unroll
          for (int r = 0; r < 4; ++r) {
            const int row = mt * 16 + quad * 4 + r;
            float v = acc[mt][nn][r] + b2v[nn];
            if (MODE == 0) v = fmaxf(v, 0.f);
            preS[row * 136 + col] = f2b(v);
          }
        }
    }
    __syncthreads();

    if (MODE == 0) {
      // LN stats from bf16 o in preS
      const int n = tid >> 3;
      const int j = tid & 7;
      float s = 0.f, sq = 0.f;
#pragma unroll
      for (int t = 0; t < 16; ++t) {
        const float v =
            __builtin_bit_cast(float, (unsigned)preS[n * 136 + j + 8 * t] << 16);
        s += v;
        sq += v * v;
      }
      s += __shfl_xor(s, 1); sq += __shfl_xor(sq, 1);
      s += __shfl_xor(s, 2); sq += __shfl_xor(sq, 2);
      s += __shfl_xor(s, 4); sq += __shfl_xor(sq, 4);
      if (j == 0) {
        const float mu = s * (1.f / H);
        const float var = sq * (1.f / H) - mu * mu;
        muS[n] = mu;
        rsS[n] = rsqrtf(var + 1e-5f);
      }
      __syncthreads();
      unsigned* ho = (unsigned*)(h_out + base);
#pragma unroll
      for (int it = 0; it < 8; ++it) {
        const int idx = it * 512 + tid * 2;
        const int row = idx >> 7;
        const int k = idx & 127;
        const unsigned pr = *(const unsigned*)&preS[row * 136 + k];
        const float mu = muS[row], rs = rsS[row];
        const float v0 = (bflo(pr) - mu) * rs * lng0 + lnb0;
        const float v1 = (bfhi(pr) - mu) * rs * lng1 + lnb1;
        ho[idx >> 1] = pack2(v0, v1);
      }
    } else {
      unsigned* ho = (unsigned*)(h_out + base);
#pragma unroll
      for (int it = 0; it < 8; ++it) {
        const int idx = it * 512 + tid * 2;
        const int row = idx >> 7;
        const int k = idx & 127;
        const unsigned pr = *(const unsigned*)&preS[row * 136 + k];
        const float v0 = bflo(pr);
        const float v1 = bfhi(pr);
        *(float2*)&emb[base + idx] = make_float2(v0, v1);
        ho[idx >> 1] = pack2(fmaxf(v0, 0.f), fmaxf(v1, 0.f));
      }
    }
    __syncthreads();
  }
}

// ---------------------------------------------------------------------------
// Mean pool: cooperative segmented reduction over sorted `batch`.
// ---------------------------------------------------------------------------
__global__ __launch_bounds__(256) void pool_kernel(
    const uint4* __restrict__ hv, const int* __restrict__ batch,
    float* __restrict__ pooled, float* __restrict__ cnt) {
  __shared__ int bs[256];
  __shared__ float smr[512];
  __shared__ int endS;
  const int tid = threadIdx.x;
  const int c0 = blockIdx.x * 256;
  const int len = min(256, N - c0);
  if (tid < len) bs[tid] = batch[c0 + tid];
  __syncthreads();

  const int nl = tid >> 4;
  const int fg = tid & 15;
  const int wave = tid >> 6;
  const int lane = tid & 63;

  int start = 0;
  while (start < len) {
    const int g = bs[start];
    if (tid == 0) endS = len;
    __syncthreads();
    for (int i = start + tid; i < len; i += 256)
      if (bs[i] != g) atomicMin(&endS, i);
    __syncthreads();
    const int end = endS;

    float a0 = 0.f, a1 = 0.f, a2 = 0.f, a3 = 0.f;
    float a4 = 0.f, a5 = 0.f, a6 = 0.f, a7 = 0.f;
    for (int i = start + nl; i < end; i += 16) {
      const uint4 u = hv[(size_t)(c0 + i) * 16 + fg];
      a0 += bflo(u.x); a1 += bfhi(u.x); a2 += bflo(u.y); a3 += bfhi(u.y);
      a4 += bflo(u.z); a5 += bfhi(u.z); a6 += bflo(u.w); a7 += bfhi(u.w);
    }
    a0 += __shfl_xor(a0, 16); a1 += __shfl_xor(a1, 16);
    a2 += __shfl_xor(a2, 16); a3 += __shfl_xor(a3, 16);
    a4 += __shfl_xor(a4, 16); a5 += __shfl_xor(a5, 16);
    a6 += __shfl_xor(a6, 16); a7 += __shfl_xor(a7, 16);
    a0 += __shfl_xor(a0, 32); a1 += __shfl_xor(a1, 32);
    a2 += __shfl_xor(a2, 32); a3 += __shfl_xor(a3, 32);
    a4 += __shfl_xor(a4, 32); a5 += __shfl_xor(a5, 32);
    a6 += __shfl_xor(a6, 32); a7 += __shfl_xor(a7, 32);
    if (lane < 16) {
      float* d = &smr[wave * 128 + lane * 8];
      d[0] = a0; d[1] = a1; d[2] = a2; d[3] = a3;
      d[4] = a4; d[5] = a5; d[6] = a6; d[7] = a7;
    }
    __syncthreads();
    if (tid < 128) {
      const float s =
          smr[tid] + smr[128 + tid] + smr[256 + tid] + smr[384 + tid];
      atomicAdd(&pooled[g * H + tid], s);
    }
    if (tid == 0) atomicAdd(&cnt[g], (float)(end - start));
    __syncthreads();
    start = end;
  }
}

// ---------------------------------------------------------------------------
// Head: pooled/cnt -> z = pooled@pw1+pb1 -> logits -> log_softmax
// ---------------------------------------------------------------------------
__global__ __launch_bounds__(128) void head_kernel(
    const float* __restrict__ pooled, const float* __restrict__ cnt,
    const float* __restrict__ pw1, const float* __restrict__ pb1,
    const float* __restrict__ pw2, const float* __restrict__ pb2,
    float* __restrict__ out_logp) {
  __shared__ float p[H];
  __shared__ float z[H];
  __shared__ float l[C];
  const int g = blockIdx.x;
  const int f = threadIdx.x;
  const float c = fmaxf(cnt[g], 1.f);
  p[f] = pooled[g * H + f] / c;
  __syncthreads();
  float a = pb1[f];
  for (int k = 0; k < H; ++k) a += p[k] * pw1[k * H + f];
  z[f] = a;
  __syncthreads();
  if (f < C) {
    float a2 = pb2[f];
    for (int k = 0; k < H; ++k) a2 += z[k] * pw2[k * C + f];
    l[f] = a2;
  }
  __syncthreads();
  if (f == 0) {
    float m = l[0];
    for (int i = 1; i < C; ++i) m = fmaxf(m, l[i]);
    float s = 0.f;
    for (int i = 0; i < C; ++i) s += expf(l[i] - m);
    const float lse = m + logf(s);
    for (int i = 0; i < C; ++i) out_logp[g * C + i] = l[i] - lse;
  }
}

extern "C" void kernel_launch(void* const* d_in, const int* in_sizes, int n_in,
                              void* d_out, int out_size, void* d_ws,
                              size_t ws_size, hipStream_t stream) {
  const float* x = (const float*)d_in[0];
  const int* ei = (const int*)d_in[1];
  const int* src = ei;
  const int* dst = ei + E;
  const int* batch = (const int*)d_in[2];
  const float* w1_0 = (const float*)d_in[3];
  const float* b1_0 = (const float*)d_in[4];
  const float* w2_0 = (const float*)d_in[5];
  const float* b2_0 = (const float*)d_in[6];
  const float* w1_1 = (const float*)d_in[7];
  const float* b1_1 = (const float*)d_in[8];
  const float* w2_1 = (const float*)d_in[9];
  const float* b2_1 = (const float*)d_in[10];
  const float* w1_2 = (const float*)d_in[11];
  const float* b1_2 = (const float*)d_in[12];
  const float* w2_2 = (const float*)d_in[13];
  const float* b2_2 = (const float*)d_in[14];
  const float* ln_g0 = (const float*)d_in[15];
  const float* ln_b0 = (const float*)d_in[16];
  const float* ln_g1 = (const float*)d_in[17];
  const float* ln_b1 = (const float*)d_in[18];
  const float* pw1 = (const float*)d_in[19];
  const float* pb1 = (const float*)d_in[20];
  const float* pw2 = (const float*)d_in[21];
  const float* pb2 = (const float*)d_in[22];

  unsigned short* xb = (unsigned short*)d_ws;          // N*H bf16
  unsigned short* hb = xb + (size_t)N * H;             // N*H bf16
  unsigned short* pre = hb + (size_t)N * H;            // N*H bf16
  float* pooled = (float*)(pre + (size_t)N * H);       // G*H
  float* cnt = pooled + (size_t)G * H;                 // G
  int* rowptr = (int*)(cnt + G);                       // N+1
  int* csr_src = rowptr + N + 1;                       // E
  int* bcnt = csr_src + E;                             // FPART
  int* sbcnt = bcnt + FPART;                           // SB
  int* sbbase = sbcnt + SB;                            // SB
  // buckets + subbuck alias `pre` (6.55 + 8.19 MB < 25.6 MB); pre is first
  // written by gather, which runs after fill3 has consumed both.
  unsigned* buckets = (unsigned*)pre;                  // FPART*BCAP
  unsigned* subbuck = buckets + (size_t)FPART * BCAP;  // SB*SCAP
  float* emb = (float*)d_out;                          // N*H fp32
  float* logp = emb + (size_t)N * H;                   // G*C

  // ---- x -> bf16 ----
  tobf_kernel<<<N * H / (256 * 8), 256, 0, stream>>>(x, (uint4*)xb);

  // ---- CSR build: bucket -> subbucket -> sbscan -> fill3(rowptr+csr) ----
  hipMemsetAsync(bcnt, 0, (size_t)(FPART + SB) * sizeof(int), stream);
  bucket_kernel<<<BBLK, 256, 0, stream>>>(src, dst, buckets, bcnt);
  subbucket_kernel<<<256, 256, 0, stream>>>(buckets, bcnt, subbuck, sbcnt);
  sbscan_kernel<<<1, 1024, 0, stream>>>(sbcnt, sbbase);
  fill3_kernel<<<SB, 256, 0, stream>>>(subbuck, sbcnt, sbbase, rowptr,
                                       csr_src);

  // ---- conv 0 ----
  gather_kernel<<<N / 16, 256, 0, stream>>>((const uint4*)xb, rowptr, csr_src,
                                            (uint4*)pre);
  mlp_kernel<0><<<N / 32, 256, 0, stream>>>(pre, w1_0, b1_0, w2_0, b2_0, ln_g0,
                                            ln_b0, hb, nullptr);
  // ---- conv 1 ----
  gather_kernel<<<N / 16, 256, 0, stream>>>((const uint4*)hb, rowptr, csr_src,
                                            (uint4*)pre);
  mlp_kernel<0><<<N / 32, 256, 0, stream>>>(pre, w1_1, b1_1, w2_1, b2_1, ln_g1,
                                            ln_b1, hb, nullptr);
  // ---- conv 2 ----
  gather_kernel<<<N / 16, 256, 0, stream>>>((const uint4*)hb, rowptr, csr_src,
                                            (uint4*)pre);
  mlp_kernel<1><<<N / 32, 256, 0, stream>>>(pre, w1_2, b1_2, w2_2, b2_2,
                                            nullptr, nullptr, hb, emb);

  // ---- pool + head ----
  hipMemsetAsync(pooled, 0, (size_t)(G * H + G) * sizeof(float), stream);
  pool_kernel<<<NBLK, 256, 0, stream>>>((const uint4*)hb, batch, pooled, cnt);
  head_kernel<<<G, 128, 0, stream>>>(pooled, cnt, pw1, pb1, pw2, pb2, logp);
}

// Round 9
// 468.048 us; speedup vs baseline: 1.0398x; 1.0398x over previous
//
#include <hip/hip_runtime.h>

typedef __bf16 bf16_t;
typedef __bf16 bf16x8 __attribute__((ext_vector_type(8)));
typedef float floatx4 __attribute__((ext_vector_type(4)));

constexpr int N = 100000;   // nodes
constexpr int E = 1600000;  // edges
constexpr int H = 128;      // feature dim
constexpr int G = 64;       // graphs
constexpr int C = 10;       // classes
constexpr int NBLK = (N + 255) / 256;  // 391

// bucket/fill: 8 dst partitions, then 125 sub-buckets of 100 nodes each.
constexpr int FPART = 8;
constexpr int FPART_SZ = (N + FPART - 1) / FPART;  // 12500
constexpr int BCHUNK = 2048;                       // edges/block (8/thread)
constexpr int BBLK = (E + BCHUNK - 1) / BCHUNK;    // 782
constexpr int BCAP = 204800;  // per-part bucket cap (E/8 + 11sigma)

constexpr int SUBP = 125;         // sub-buckets per partition
constexpr int SUBSZ = 100;        // nodes per sub-bucket (8*125*100 == N)
constexpr int SB = FPART * SUBP;  // 1000
constexpr int SCAP = 2048;        // sub-bucket cap (mean 1600 + 11sigma)
constexpr int SCHUNK = 2048;      // entries per subbucket chunk (occupancy!)
constexpr int SBBLK = 1024;       // subbucket grid (3-4 blocks/CU)

__device__ inline float bflo(unsigned u) {
  return __builtin_bit_cast(float, u << 16);
}
__device__ inline float bfhi(unsigned u) {
  return __builtin_bit_cast(float, u & 0xffff0000u);
}
__device__ inline unsigned short f2b(float f) {
  return __builtin_bit_cast(unsigned short, (bf16_t)f);
}
__device__ inline unsigned pack2(float a, float b) {
  return (unsigned)f2b(a) | ((unsigned)f2b(b) << 16);
}

// ---------------------------------------------------------------------------
// fp32 -> bf16 convert (x once per call).
// ---------------------------------------------------------------------------
__global__ __launch_bounds__(256) void tobf_kernel(const float* __restrict__ x,
                                                   uint4* __restrict__ xb) {
  const int g = blockIdx.x * 256 + threadIdx.x;
  const float4 a = *(const float4*)(x + (size_t)g * 8);
  const float4 b = *(const float4*)(x + (size_t)g * 8 + 4);
  uint4 o;
  o.x = pack2(a.x, a.y);
  o.y = pack2(a.z, a.w);
  o.z = pack2(b.x, b.y);
  o.w = pack2(b.z, b.w);
  xb[g] = o;
}

// ---------------------------------------------------------------------------
// Bucket pass v4: single edge-list read, ballot-rank slot assignment, LDS
// staging, coalesced partition-segment flush. No deg atomics.
// ---------------------------------------------------------------------------
__global__ __launch_bounds__(256) void bucket_kernel(
    const int* __restrict__ src, const int* __restrict__ dst,
    unsigned* __restrict__ buckets, int* __restrict__ bcnt) {
  __shared__ int offS[4][FPART];      // per-wave running counts
  __shared__ int waveExcl[4][FPART];  // per-wave exclusive base per part
  __shared__ int cntA[FPART];         // block totals per part
  __shared__ int blockExcl[FPART];    // in-block exclusive base per part
  __shared__ int baseS[FPART];        // global base per part
  __shared__ unsigned stage[BCHUNK];  // partition-ordered staging (8KB)
  const int tid = threadIdx.x;
  const int wave = tid >> 6;
  const int lane = tid & 63;
  if (tid < 32) ((int*)offS)[tid] = 0;
  __syncthreads();

  const int e0 = blockIdx.x * BCHUNK + tid * 8;
  int d[8], s[8];
  int nv = 0;
  if (e0 + 8 <= E) {
    const int4 da = *(const int4*)(dst + e0);
    const int4 db = *(const int4*)(dst + e0 + 4);
    const int4 sa = *(const int4*)(src + e0);
    const int4 sb = *(const int4*)(src + e0 + 4);
    d[0] = da.x; d[1] = da.y; d[2] = da.z; d[3] = da.w;
    d[4] = db.x; d[5] = db.y; d[6] = db.z; d[7] = db.w;
    s[0] = sa.x; s[1] = sa.y; s[2] = sa.z; s[3] = sa.w;
    s[4] = sb.x; s[5] = sb.y; s[6] = sb.z; s[7] = sb.w;
    nv = 8;
  } else {
    nv = (e0 < E) ? (E - e0) : 0;
    if (nv > 8) nv = 8;
    for (int j = 0; j < nv; ++j) {
      d[j] = dst[e0 + j];
      s[j] = src[e0 + j];
    }
    for (int j = nv; j < 8; ++j) { d[j] = 0; s[j] = 0; }
  }

  const unsigned long long below = (1ull << lane) - 1ull;

  int pj[8];     // partition of edge j
  int slotW[8];  // within-wave slot (base + rank)

#pragma unroll
  for (int j = 0; j < 8; ++j) {
    const bool valid = (j < nv);
    const int p = d[j] / FPART_SZ;
    pj[j] = p;
    unsigned long long mown = 0;
#pragma unroll
    for (int q = 0; q < FPART; ++q) {
      const unsigned long long mq = __ballot(valid && (p == q));
      if (p == q) mown = mq;
    }
    const int cnt = (int)__popcll(mown);
    const int rank = (int)__popcll(mown & below);
    const int base = offS[wave][p];
    if (valid && rank == 0) offS[wave][p] = base + cnt;
    slotW[j] = base + rank;
  }
  __syncthreads();

  // cross-wave scan + global reservation
  if (tid < FPART) {
    int running = 0;
#pragma unroll
    for (int w = 0; w < 4; ++w) {
      waveExcl[w][tid] = running;
      running += offS[w][tid];
    }
    cntA[tid] = running;
    baseS[tid] = atomicAdd(&bcnt[tid], running);
  }
  __syncthreads();
  if (tid < FPART) {
    int ex = 0;
    for (int q = 0; q < tid; ++q) ex += cntA[q];
    blockExcl[tid] = ex;
  }
  __syncthreads();

  // stage: partition-contiguous order within the block
#pragma unroll
  for (int j = 0; j < 8; ++j) {
    if (j < nv) {
      const int p = pj[j];
      stage[blockExcl[p] + waveExcl[wave][p] + slotW[j]] =
          ((unsigned)s[j] << 14) | (unsigned)(d[j] - p * FPART_SZ);
    }
  }
  __syncthreads();

  // flush: coalesced contiguous stores per partition segment
#pragma unroll
  for (int p = 0; p < FPART; ++p) {
    const int c = cntA[p];
    const int gb = p * BCAP + baseS[p];
    const int lb = blockExcl[p];
    for (int i = tid; i < c; i += 256) buckets[gb + i] = stage[lb + i];
  }
}

// ---------------------------------------------------------------------------
// Sub-bucket pass: partition buckets -> 1000 sub-buckets of exactly 100
// nodes. SCHUNK=2048 + grid 1024: ~780 active chunk-blocks (3-4/CU) instead
// of the old 196 at 1 block/CU -- occupancy was the limiter, not coalescing
// (flush segments drop 260B->65B; a wave's 64 contiguous stores still fill
// ~2 full 64B-line runs).
// ---------------------------------------------------------------------------
__global__ __launch_bounds__(256) void subbucket_kernel(
    const unsigned* __restrict__ buckets, const int* __restrict__ bcnt,
    unsigned* __restrict__ subbuck, int* __restrict__ sbcnt) {
  __shared__ unsigned stage[SCHUNK];  // 8 KB
  __shared__ int cntA[SUBP];
  __shared__ int cntB[SUBP];
  __shared__ int exclS[SUBP];
  __shared__ int gbase[SUBP];
  __shared__ int scanbuf[128];
  const int part = blockIdx.x & (FPART - 1);
  const int blk = blockIdx.x >> 3;
  const int nblk = gridDim.x >> 3;
  const int tid = threadIdx.x;
  const int cnt = bcnt[part];
  const unsigned* b = buckets + part * BCAP;

  for (int c0 = blk * SCHUNK; c0 < cnt; c0 += nblk * SCHUNK) {
    const int m = min(SCHUNK, cnt - c0);
    if (tid < SUBP) {
      cntA[tid] = 0;
      cntB[tid] = 0;
    }
    __syncthreads();
    // pass A: count per sub-bucket
    for (int i = tid; i < m; i += 256) {
      const unsigned ent = b[c0 + i];
      atomicAdd(&cntA[(int)(ent & 0x3FFFu) / SUBSZ], 1);
    }
    __syncthreads();
    // scan over 125 (Hillis-Steele on 128)
    if (tid < 128) scanbuf[tid] = (tid < SUBP) ? cntA[tid] : 0;
    __syncthreads();
    for (int off = 1; off < 128; off <<= 1) {
      int v = 0;
      if (tid < 128 && tid >= off) v = scanbuf[tid - off];
      __syncthreads();
      if (tid < 128) scanbuf[tid] += v;
      __syncthreads();
    }
    if (tid < SUBP) {
      exclS[tid] = scanbuf[tid] - cntA[tid];
      gbase[tid] = atomicAdd(&sbcnt[part * SUBP + tid], cntA[tid]);
    }
    __syncthreads();
    // pass B: place into LDS stage, sub-bucket-ordered (re-read is L2-hot)
    for (int i = tid; i < m; i += 256) {
      const unsigned ent = b[c0 + i];
      const int s = (int)(ent & 0x3FFFu) / SUBSZ;
      const int r = atomicAdd(&cntB[s], 1);
      stage[exclS[s] + r] = ent;
    }
    __syncthreads();
    // flush: coalesced within each sub-bucket segment
    for (int i = tid; i < m; i += 256) {
      const unsigned ent = stage[i];
      const int s = (int)(ent & 0x3FFFu) / SUBSZ;
      subbuck[(size_t)(part * SUBP + s) * SCAP + gbase[s] + (i - exclS[s])] =
          ent;
    }
    __syncthreads();
  }
}

// ---------------------------------------------------------------------------
// Scan of the 1000 sub-bucket counts -> exclusive bases (coarse rowptr).
// ---------------------------------------------------------------------------
__global__ __launch_bounds__(1024) void sbscan_kernel(
    const int* __restrict__ sbcnt, int* __restrict__ sbbase) {
  __shared__ int p[1024];
  const int t = threadIdx.x;
  p[t] = (t < SB) ? sbcnt[t] : 0;
  __syncthreads();
  for (int off = 1; off < 1024; off <<= 1) {
    int v = 0;
    if (t >= off) v = p[t - off];
    __syncthreads();
    p[t] += v;
    __syncthreads();
  }
  if (t < SB) sbbase[t] = p[t] - sbcnt[t];
}

// ---------------------------------------------------------------------------
// Fill v4: one block per sub-bucket. LDS counting sort over 100 nodes;
// local histogram scan yields rowptr for free; contiguous coalesced store.
// ---------------------------------------------------------------------------
__global__ __launch_bounds__(256) void fill3_kernel(
    const unsigned* __restrict__ subbuck, const int* __restrict__ sbcnt,
    const int* __restrict__ sbbase, int* __restrict__ rowptr,
    int* __restrict__ csr_src) {
  __shared__ unsigned ld[SCAP];  // 8 KB
  __shared__ int stageS[SCAP];   // 8 KB
  __shared__ int hist[SUBSZ];
  __shared__ int cntB[SUBSZ];
  __shared__ int exclS[SUBSZ];
  __shared__ int scanbuf[128];
  const int sb = blockIdx.x;
  const int part = sb / SUBP;
  const int subl = sb % SUBP;
  const int n0 = part * FPART_SZ + subl * SUBSZ;
  const int tid = threadIdx.x;
  const int cnt = sbcnt[sb];
  const int base = sbbase[sb];
  const unsigned* b = subbuck + (size_t)sb * SCAP;
  if (tid < SUBSZ) {
    hist[tid] = 0;
    cntB[tid] = 0;
  }
  __syncthreads();
  for (int i = tid; i < cnt; i += 256) {
    const unsigned ent = b[i];
    ld[i] = ent;
    atomicAdd(&hist[(int)(ent & 0x3FFFu) - subl * SUBSZ], 1);
  }
  __syncthreads();
  if (tid < 128) scanbuf[tid] = (tid < SUBSZ) ? hist[tid] : 0;
  __syncthreads();
  for (int off = 1; off < 128; off <<= 1) {
    int v = 0;
    if (tid < 128 && tid >= off) v = scanbuf[tid - off];
    __syncthreads();
    if (tid < 128) scanbuf[tid] += v;
    __syncthreads();
  }
  if (tid < SUBSZ) {
    const int ex = scanbuf[tid] - hist[tid];
    exclS[tid] = ex;
    rowptr[n0 + tid] = base + ex;  // per-node rowptr, derived locally
  }
  if (sb == SB - 1 && tid == 0) rowptr[N] = base + cnt;
  __syncthreads();
  for (int i = tid; i < cnt; i += 256) {
    const unsigned ent = ld[i];
    const int j = (int)(ent & 0x3FFFu) - subl * SUBSZ;
    const int r = atomicAdd(&cntB[j], 1);
    stageS[exclS[j] + r] = (int)(ent >> 14);
  }
  __syncthreads();
  for (int i = tid; i < cnt; i += 256) csr_src[base + i] = stageS[i];
}

// ---------------------------------------------------------------------------
// Gather aggregation (bf16): pre[i] = h[i] + sum_{j in nbrs(i)} h[j]
// 16 lanes/node, uint4/lane, unroll 4. Near-roofline for random 256B fetch:
// 3.6 TB/s, FETCH at the 8-XCD x 25.6MB structural floor (measured R5-R8).
// Deeper SW pipelining measured NEUTRAL-to-negative (R8: VGPR 24->36,
// occ 68->59, dur +1us) -- keep the low-VGPR form.
// ---------------------------------------------------------------------------
__global__ __launch_bounds__(256) void gather_kernel(
    const uint4* __restrict__ h, const int* __restrict__ rowptr,
    const int* __restrict__ csr_src, uint4* __restrict__ pre) {
  const int node = blockIdx.x * 16 + (threadIdx.x >> 4);
  const int l = threadIdx.x & 15;
  const int r0 = rowptr[node];
  const int r1 = rowptr[node + 1];
  const uint4 v = h[(size_t)node * 16 + l];
  float a0 = bflo(v.x), a1 = bfhi(v.x), a2 = bflo(v.y), a3 = bfhi(v.y);
  float a4 = bflo(v.z), a5 = bfhi(v.z), a6 = bflo(v.w), a7 = bfhi(v.w);
  int s = r0;
  for (; s + 3 < r1; s += 4) {
    const int i0 = csr_src[s], i1 = csr_src[s + 1];
    const int i2 = csr_src[s + 2], i3 = csr_src[s + 3];
    const uint4 u0 = h[(size_t)i0 * 16 + l];
    const uint4 u1 = h[(size_t)i1 * 16 + l];
    const uint4 u2 = h[(size_t)i2 * 16 + l];
    const uint4 u3 = h[(size_t)i3 * 16 + l];
    a0 += bflo(u0.x); a1 += bfhi(u0.x); a2 += bflo(u0.y); a3 += bfhi(u0.y);
    a4 += bflo(u0.z); a5 += bfhi(u0.z); a6 += bflo(u0.w); a7 += bfhi(u0.w);
    a0 += bflo(u1.x); a1 += bfhi(u1.x); a2 += bflo(u1.y); a3 += bfhi(u1.y);
    a4 += bflo(u1.z); a5 += bfhi(u1.z); a6 += bflo(u1.w); a7 += bfhi(u1.w);
    a0 += bflo(u2.x); a1 += bfhi(u2.x); a2 += bflo(u2.y); a3 += bfhi(u2.y);
    a4 += bflo(u2.z); a5 += bfhi(u2.z); a6 += bflo(u2.w); a7 += bfhi(u2.w);
    a0 += bflo(u3.x); a1 += bfhi(u3.x); a2 += bflo(u3.y); a3 += bfhi(u3.y);
    a4 += bflo(u3.z); a5 += bfhi(u3.z); a6 += bflo(u3.w); a7 += bfhi(u3.w);
  }
  for (; s < r1; ++s) {
    const uint4 u = h[(size_t)csr_src[s] * 16 + l];
    a0 += bflo(u.x); a1 += bfhi(u.x); a2 += bflo(u.y); a3 += bfhi(u.y);
    a4 += bflo(u.z); a5 += bfhi(u.z); a6 += bflo(u.w); a7 += bfhi(u.w);
  }
  uint4 o;
  o.x = pack2(a0, a1);
  o.y = pack2(a2, a3);
  o.z = pack2(a4, a5);
  o.w = pack2(a6, a7);
  pre[(size_t)node * 16 + l] = o;
}

// ---------------------------------------------------------------------------
// MFMA bf16 GIN MLP (separate from gather: fusion costs gather occupancy,
// measured R6). Grid 2048 (1.53 tiles/block amortizes weight preload;
// N/32 grid measured slightly worse, R8). preS + hidS bf16 136-padded.
// MODE 0: h_out = bf16(LN(relu(o))); MODE 1: emb = o, h_out = relu(o).
// ---------------------------------------------------------------------------
template <int MODE>
__global__ __launch_bounds__(256) void mlp_kernel(
    const unsigned short* __restrict__ pre_g,  // bf16 N x 128
    const float* __restrict__ w1, const float* __restrict__ b1,
    const float* __restrict__ w2, const float* __restrict__ b2,
    const float* __restrict__ lng, const float* __restrict__ lnb,
    unsigned short* __restrict__ h_out,        // bf16 N x 128
    float* __restrict__ emb) {
  __shared__ unsigned short preS[32 * 136];
  __shared__ unsigned short hidS[32 * 136];
  __shared__ float muS[32];
  __shared__ float rsS[32];

  const int tid = threadIdx.x;
  const int wave = tid >> 6;
  const int lane = tid & 63;
  const int quad = lane >> 4;
  const int l16 = lane & 15;

  union F8 { bf16x8 v; bf16_t e[8]; };

  bf16x8 w1f[4][2], w2f[4][2];
#pragma unroll
  for (int nn = 0; nn < 2; ++nn) {
    const int col = wave * 32 + nn * 16 + l16;
#pragma unroll
    for (int kt = 0; kt < 4; ++kt) {
      F8 t1, t2;
#pragma unroll
      for (int j = 0; j < 8; ++j) {
        const int k = kt * 32 + quad * 8 + j;
        t1.e[j] = (bf16_t)w1[k * H + col];
        t2.e[j] = (bf16_t)w2[k * H + col];
      }
      w1f[kt][nn] = t1.v;
      w2f[kt][nn] = t2.v;
    }
  }
  const float b1v[2] = {b1[wave * 32 + l16], b1[wave * 32 + 16 + l16]};
  const float b2v[2] = {b2[wave * 32 + l16], b2[wave * 32 + 16 + l16]};
  float lng0 = 0.f, lng1 = 0.f, lnb0 = 0.f, lnb1 = 0.f;
  const int c2 = (tid * 2) & 127;
  if (MODE == 0) {
    lng0 = lng[c2]; lng1 = lng[c2 + 1];
    lnb0 = lnb[c2]; lnb1 = lnb[c2 + 1];
  }

  for (int tile = blockIdx.x; tile < N / 32; tile += gridDim.x) {
    const size_t base = (size_t)tile * 32 * H;
    {
      const uint4* srcp = (const uint4*)(pre_g + base);
#pragma unroll
      for (int it = 0; it < 2; ++it) {
        const int chunk = it * 256 + tid;
        const int row = chunk >> 4;
        const int colc = (chunk & 15) * 8;
        *(uint4*)&preS[row * 136 + colc] = srcp[chunk];
      }
    }
    __syncthreads();

    // GEMM1: hid = relu(pre @ W1 + b1)
    {
      floatx4 acc[2][2];
#pragma unroll
      for (int i = 0; i < 2; ++i)
#pragma unroll
        for (int j = 0; j < 2; ++j) acc[i][j] = {0.f, 0.f, 0.f, 0.f};
#pragma unroll
      for (int kt = 0; kt < 4; ++kt) {
        const int kc = kt * 32 + quad * 8;
        const bf16x8 a0 =
            __builtin_bit_cast(bf16x8, *(const uint4*)&preS[l16 * 136 + kc]);
        const bf16x8 a1 = __builtin_bit_cast(
            bf16x8, *(const uint4*)&preS[(16 + l16) * 136 + kc]);
        acc[0][0] = __builtin_amdgcn_mfma_f32_16x16x32_bf16(a0, w1f[kt][0],
                                                            acc[0][0], 0, 0, 0);
        acc[0][1] = __builtin_amdgcn_mfma_f32_16x16x32_bf16(a0, w1f[kt][1],
                                                            acc[0][1], 0, 0, 0);
        acc[1][0] = __builtin_amdgcn_mfma_f32_16x16x32_bf16(a1, w1f[kt][0],
                                                            acc[1][0], 0, 0, 0);
        acc[1][1] = __builtin_amdgcn_mfma_f32_16x16x32_bf16(a1, w1f[kt][1],
                                                            acc[1][1], 0, 0, 0);
      }
#pragma unroll
      for (int mt = 0; mt < 2; ++mt)
#pragma unroll
        for (int nn = 0; nn < 2; ++nn) {
          const int col = wave * 32 + nn * 16 + l16;
#pragma unroll
          for (int r = 0; r < 4; ++r) {
            const int row = mt * 16 + quad * 4 + r;
            const float v = fmaxf(acc[mt][nn][r] + b1v[nn], 0.f);
            hidS[row * 136 + col] = f2b(v);
          }
        }
    }
    __syncthreads();  // hidS ready; also: all preS reads (GEMM1) done

    // GEMM2: o = hid @ W2 + b2 ; write o (bf16) back into preS
    {
      floatx4 acc[2][2];
#pragma unroll
      for (int i = 0; i < 2; ++i)
#pragma unroll
        for (int j = 0; j < 2; ++j) acc[i][j] = {0.f, 0.f, 0.f, 0.f};
#pragma unroll
      for (int kt = 0; kt < 4; ++kt) {
        const int kc = kt * 32 + quad * 8;
        const bf16x8 a0 =
            __builtin_bit_cast(bf16x8, *(const uint4*)&hidS[l16 * 136 + kc]);
        const bf16x8 a1 = __builtin_bit_cast(
            bf16x8, *(const uint4*)&hidS[(16 + l16) * 136 + kc]);
        acc[0][0] = __builtin_amdgcn_mfma_f32_16x16x32_bf16(a0, w2f[kt][0],
                                                            acc[0][0], 0, 0, 0);
        acc[0][1] = __builtin_amdgcn_mfma_f32_16x16x32_bf16(a0, w2f[kt][1],
                                                            acc[0][1], 0, 0, 0);
        acc[1][0] = __builtin_amdgcn_mfma_f32_16x16x32_bf16(a1, w2f[kt][0],
                                                            acc[1][0], 0, 0, 0);
        acc[1][1] = __builtin_amdgcn_mfma_f32_16x16x32_bf16(a1, w2f[kt][1],
                                                            acc[1][1], 0, 0, 0);
      }
#pragma unroll
      for (int mt = 0; mt < 2; ++mt)
#pragma unroll
        for (int nn = 0; nn < 2; ++nn) {
          const int col = wave * 32 + nn * 16 + l16;
#pragma unroll
          for (int r = 0; r < 4; ++r) {
            const int row = mt * 16 + quad * 4 + r;
            float v = acc[mt][nn][r] + b2v[nn];
            if (MODE == 0) v = fmaxf(v, 0.f);
            preS[row * 136 + col] = f2b(v);
          }
        }
    }
    __syncthreads();

    if (MODE == 0) {
      // LN stats from bf16 o in preS
      const int n = tid >> 3;
      const int j = tid & 7;
      float s = 0.f, sq = 0.f;
#pragma unroll
      for (int t = 0; t < 16; ++t) {
        const float v =
            __builtin_bit_cast(float, (unsigned)preS[n * 136 + j + 8 * t] << 16);
        s += v;
        sq += v * v;
      }
      s += __shfl_xor(s, 1); sq += __shfl_xor(sq, 1);
      s += __shfl_xor(s, 2); sq += __shfl_xor(sq, 2);
      s += __shfl_xor(s, 4); sq += __shfl_xor(sq, 4);
      if (j == 0) {
        const float mu = s * (1.f / H);
        const float var = sq * (1.f / H) - mu * mu;
        muS[n] = mu;
        rsS[n] = rsqrtf(var + 1e-5f);
      }
      __syncthreads();
      unsigned* ho = (unsigned*)(h_out + base);
#pragma unroll
      for (int it = 0; it < 8; ++it) {
        const int idx = it * 512 + tid * 2;
        const int row = idx >> 7;
        const int k = idx & 127;
        const unsigned pr = *(const unsigned*)&preS[row * 136 + k];
        const float mu = muS[row], rs = rsS[row];
        const float v0 = (bflo(pr) - mu) * rs * lng0 + lnb0;
        const float v1 = (bfhi(pr) - mu) * rs * lng1 + lnb1;
        ho[idx >> 1] = pack2(v0, v1);
      }
    } else {
      unsigned* ho = (unsigned*)(h_out + base);
#pragma unroll
      for (int it = 0; it < 8; ++it) {
        const int idx = it * 512 + tid * 2;
        const int row = idx >> 7;
        const int k = idx & 127;
        const unsigned pr = *(const unsigned*)&preS[row * 136 + k];
        const float v0 = bflo(pr);
        const float v1 = bfhi(pr);
        *(float2*)&emb[base + idx] = make_float2(v0, v1);
        ho[idx >> 1] = pack2(fmaxf(v0, 0.f), fmaxf(v1, 0.f));
      }
    }
    __syncthreads();
  }
}

// ---------------------------------------------------------------------------
// Mean pool: cooperative segmented reduction over sorted `batch`.
// ---------------------------------------------------------------------------
__global__ __launch_bounds__(256) void pool_kernel(
    const uint4* __restrict__ hv, const int* __restrict__ batch,
    float* __restrict__ pooled, float* __restrict__ cnt) {
  __shared__ int bs[256];
  __shared__ float smr[512];
  __shared__ int endS;
  const int tid = threadIdx.x;
  const int c0 = blockIdx.x * 256;
  const int len = min(256, N - c0);
  if (tid < len) bs[tid] = batch[c0 + tid];
  __syncthreads();

  const int nl = tid >> 4;
  const int fg = tid & 15;
  const int wave = tid >> 6;
  const int lane = tid & 63;

  int start = 0;
  while (start < len) {
    const int g = bs[start];
    if (tid == 0) endS = len;
    __syncthreads();
    for (int i = start + tid; i < len; i += 256)
      if (bs[i] != g) atomicMin(&endS, i);
    __syncthreads();
    const int end = endS;

    float a0 = 0.f, a1 = 0.f, a2 = 0.f, a3 = 0.f;
    float a4 = 0.f, a5 = 0.f, a6 = 0.f, a7 = 0.f;
    for (int i = start + nl; i < end; i += 16) {
      const uint4 u = hv[(size_t)(c0 + i) * 16 + fg];
      a0 += bflo(u.x); a1 += bfhi(u.x); a2 += bflo(u.y); a3 += bfhi(u.y);
      a4 += bflo(u.z); a5 += bfhi(u.z); a6 += bflo(u.w); a7 += bfhi(u.w);
    }
    a0 += __shfl_xor(a0, 16); a1 += __shfl_xor(a1, 16);
    a2 += __shfl_xor(a2, 16); a3 += __shfl_xor(a3, 16);
    a4 += __shfl_xor(a4, 16); a5 += __shfl_xor(a5, 16);
    a6 += __shfl_xor(a6, 16); a7 += __shfl_xor(a7, 16);
    a0 += __shfl_xor(a0, 32); a1 += __shfl_xor(a1, 32);
    a2 += __shfl_xor(a2, 32); a3 += __shfl_xor(a3, 32);
    a4 += __shfl_xor(a4, 32); a5 += __shfl_xor(a5, 32);
    a6 += __shfl_xor(a6, 32); a7 += __shfl_xor(a7, 32);
    if (lane < 16) {
      float* d = &smr[wave * 128 + lane * 8];
      d[0] = a0; d[1] = a1; d[2] = a2; d[3] = a3;
      d[4] = a4; d[5] = a5; d[6] = a6; d[7] = a7;
    }
    __syncthreads();
    if (tid < 128) {
      const float s =
          smr[tid] + smr[128 + tid] + smr[256 + tid] + smr[384 + tid];
      atomicAdd(&pooled[g * H + tid], s);
    }
    if (tid == 0) atomicAdd(&cnt[g], (float)(end - start));
    __syncthreads();
    start = end;
  }
}

// ---------------------------------------------------------------------------
// Head: pooled/cnt -> z = pooled@pw1+pb1 -> logits -> log_softmax
// ---------------------------------------------------------------------------
__global__ __launch_bounds__(128) void head_kernel(
    const float* __restrict__ pooled, const float* __restrict__ cnt,
    const float* __restrict__ pw1, const float* __restrict__ pb1,
    const float* __restrict__ pw2, const float* __restrict__ pb2,
    float* __restrict__ out_logp) {
  __shared__ float p[H];
  __shared__ float z[H];
  __shared__ float l[C];
  const int g = blockIdx.x;
  const int f = threadIdx.x;
  const float c = fmaxf(cnt[g], 1.f);
  p[f] = pooled[g * H + f] / c;
  __syncthreads();
  float a = pb1[f];
  for (int k = 0; k < H; ++k) a += p[k] * pw1[k * H + f];
  z[f] = a;
  __syncthreads();
  if (f < C) {
    float a2 = pb2[f];
    for (int k = 0; k < H; ++k) a2 += z[k] * pw2[k * C + f];
    l[f] = a2;
  }
  __syncthreads();
  if (f == 0) {
    float m = l[0];
    for (int i = 1; i < C; ++i) m = fmaxf(m, l[i]);
    float s = 0.f;
    for (int i = 0; i < C; ++i) s += expf(l[i] - m);
    const float lse = m + logf(s);
    for (int i = 0; i < C; ++i) out_logp[g * C + i] = l[i] - lse;
  }
}

extern "C" void kernel_launch(void* const* d_in, const int* in_sizes, int n_in,
                              void* d_out, int out_size, void* d_ws,
                              size_t ws_size, hipStream_t stream) {
  const float* x = (const float*)d_in[0];
  const int* ei = (const int*)d_in[1];
  const int* src = ei;
  const int* dst = ei + E;
  const int* batch = (const int*)d_in[2];
  const float* w1_0 = (const float*)d_in[3];
  const float* b1_0 = (const float*)d_in[4];
  const float* w2_0 = (const float*)d_in[5];
  const float* b2_0 = (const float*)d_in[6];
  const float* w1_1 = (const float*)d_in[7];
  const float* b1_1 = (const float*)d_in[8];
  const float* w2_1 = (const float*)d_in[9];
  const float* b2_1 = (const float*)d_in[10];
  const float* w1_2 = (const float*)d_in[11];
  const float* b1_2 = (const float*)d_in[12];
  const float* w2_2 = (const float*)d_in[13];
  const float* b2_2 = (const float*)d_in[14];
  const float* ln_g0 = (const float*)d_in[15];
  const float* ln_b0 = (const float*)d_in[16];
  const float* ln_g1 = (const float*)d_in[17];
  const float* ln_b1 = (const float*)d_in[18];
  const float* pw1 = (const float*)d_in[19];
  const float* pb1 = (const float*)d_in[20];
  const float* pw2 = (const float*)d_in[21];
  const float* pb2 = (const float*)d_in[22];

  unsigned short* xb = (unsigned short*)d_ws;          // N*H bf16
  unsigned short* hb = xb + (size_t)N * H;             // N*H bf16
  unsigned short* pre = hb + (size_t)N * H;            // N*H bf16
  float* pooled = (float*)(pre + (size_t)N * H);       // G*H
  float* cnt = pooled + (size_t)G * H;                 // G
  int* rowptr = (int*)(cnt + G);                       // N+1
  int* csr_src = rowptr + N + 1;                       // E
  int* bcnt = csr_src + E;                             // FPART
  int* sbcnt = bcnt + FPART;                           // SB
  int* sbbase = sbcnt + SB;                            // SB
  // buckets + subbuck alias `pre` (6.55 + 8.19 MB < 25.6 MB); pre is first
  // written by gather, which runs after fill3 has consumed both.
  unsigned* buckets = (unsigned*)pre;                  // FPART*BCAP
  unsigned* subbuck = buckets + (size_t)FPART * BCAP;  // SB*SCAP
  float* emb = (float*)d_out;                          // N*H fp32
  float* logp = emb + (size_t)N * H;                   // G*C

  // ---- x -> bf16 ----
  tobf_kernel<<<N * H / (256 * 8), 256, 0, stream>>>(x, (uint4*)xb);

  // ---- CSR build: bucket -> subbucket -> sbscan -> fill3(rowptr+csr) ----
  hipMemsetAsync(bcnt, 0, (size_t)(FPART + SB) * sizeof(int), stream);
  bucket_kernel<<<BBLK, 256, 0, stream>>>(src, dst, buckets, bcnt);
  subbucket_kernel<<<SBBLK, 256, 0, stream>>>(buckets, bcnt, subbuck, sbcnt);
  sbscan_kernel<<<1, 1024, 0, stream>>>(sbcnt, sbbase);
  fill3_kernel<<<SB, 256, 0, stream>>>(subbuck, sbcnt, sbbase, rowptr,
                                       csr_src);

  // ---- conv 0 ----
  gather_kernel<<<N / 16, 256, 0, stream>>>((const uint4*)xb, rowptr, csr_src,
                                            (uint4*)pre);
  mlp_kernel<0><<<2048, 256, 0, stream>>>(pre, w1_0, b1_0, w2_0, b2_0, ln_g0,
                                          ln_b0, hb, nullptr);
  // ---- conv 1 ----
  gather_kernel<<<N / 16, 256, 0, stream>>>((const uint4*)hb, rowptr, csr_src,
                                            (uint4*)pre);
  mlp_kernel<0><<<2048, 256, 0, stream>>>(pre, w1_1, b1_1, w2_1, b2_1, ln_g1,
                                          ln_b1, hb, nullptr);
  // ---- conv 2 ----
  gather_kernel<<<N / 16, 256, 0, stream>>>((const uint4*)hb, rowptr, csr_src,
                                            (uint4*)pre);
  mlp_kernel<1><<<2048, 256, 0, stream>>>(pre, w1_2, b1_2, w2_2, b2_2, nullptr,
                                          nullptr, hb, emb);

  // ---- pool + head ----
  hipMemsetAsync(pooled, 0, (size_t)(G * H + G) * sizeof(float), stream);
  pool_kernel<<<NBLK, 256, 0, stream>>>((const uint4*)hb, batch, pooled, cnt);
  head_kernel<<<G, 128, 0, stream>>>(pooled, cnt, pw1, pb1, pw2, pb2, logp);
}